// Round 20
// baseline (99.912 us; speedup 1.0000x reference)
//
#include <hip/hip_runtime.h>
#include <hip/hip_bf16.h>
#include <math.h>

constexpr int cB = 8, cNQ = 300, cC = 256, cH = 64, cW = 64, cHEADS = 8, cHD = 32;
constexpr int cHW = cH * cW;
constexpr int cM = cB * cNQ;  // 2400
constexpr float cSCALE = 0.1767766952966369f; // 32^-0.5

typedef __bf16 bf16_t;
typedef bf16_t bf16x4 __attribute__((ext_vector_type(4)));
typedef bf16_t bf16x8 __attribute__((ext_vector_type(8)));
typedef float f32x4 __attribute__((ext_vector_type(4)));
typedef _Float16 f16_t;
typedef f16_t f16x2 __attribute__((ext_vector_type(2)));
typedef f16_t f16x8 __attribute__((ext_vector_type(8)));

__device__ __forceinline__ float dot2acc(f16x2 a, f16x2 b, float c) {
#if __has_builtin(__builtin_amdgcn_fdot2)
  return __builtin_amdgcn_fdot2(a, b, c, false);
#else
  return c + (float)a.x * (float)b.x + (float)a.y * (float)b.y;
#endif
}

// ---------------------------------------------------------------------------
// MFMA GEMM: out[m,n] = (dot(X[m,:],Wt[n,:]) + bias[n])*scale. f16 out if out_h.
__global__ __launch_bounds__(256) void proj_mfma_k(
    const float* __restrict__ X, const float* __restrict__ Wt,
    const float* __restrict__ bias, float* __restrict__ out,
    f16_t* __restrict__ out_h, float scale, int M) {
  __shared__ bf16_t Xs[128 * 64];
  __shared__ bf16_t Ws[64 * 64];
  int m0 = blockIdx.x * 128;
  int o0 = blockIdx.y * 64;
  int tid = threadIdx.x;
  int lane = tid & 63, w = tid >> 6;
  int moff = (w & 1) * 64, ooff = (w >> 1) * 32;
  int l15 = lane & 15, l4 = lane >> 4;
  int srow = tid >> 1;
  int schalf = (tid & 1) * 32;
  int wo_l = tid >> 2;
  int wcg = (tid & 3) * 16;

  f32x4 acc[4][2];
#pragma unroll
  for (int m = 0; m < 4; ++m)
#pragma unroll
    for (int n = 0; n < 2; ++n) acc[m][n] = (f32x4){0.f, 0.f, 0.f, 0.f};

  for (int c0 = 0; c0 < cC; c0 += 64) {
    {
      int mrow = min(m0 + srow, M - 1);
      const float4* xr = (const float4*)(X + (size_t)mrow * cC + c0 + schalf);
      int sw = (srow & 7) * 8;
#pragma unroll
      for (int i = 0; i < 4; ++i) {
        float4 a = xr[i * 2], b4 = xr[i * 2 + 1];
        bf16x8 v = {(bf16_t)a.x, (bf16_t)a.y, (bf16_t)a.z, (bf16_t)a.w,
                    (bf16_t)b4.x, (bf16_t)b4.y, (bf16_t)b4.z, (bf16_t)b4.w};
        *(bf16x8*)&Xs[srow * 64 + ((schalf + i * 8) ^ sw)] = v;
      }
    }
    {
      const float4* wr = (const float4*)(Wt + (size_t)(o0 + wo_l) * cC + c0 + wcg);
      float4 a = wr[0], b4 = wr[1], c4 = wr[2], d4 = wr[3];
      bf16x8 w0 = {(bf16_t)a.x, (bf16_t)a.y, (bf16_t)a.z, (bf16_t)a.w,
                   (bf16_t)b4.x, (bf16_t)b4.y, (bf16_t)b4.z, (bf16_t)b4.w};
      bf16x8 w1 = {(bf16_t)c4.x, (bf16_t)c4.y, (bf16_t)c4.z, (bf16_t)c4.w,
                   (bf16_t)d4.x, (bf16_t)d4.y, (bf16_t)d4.z, (bf16_t)d4.w};
      int sw = (wo_l & 7) * 8;
      *(bf16x8*)&Ws[wo_l * 64 + (wcg ^ sw)] = w0;
      *(bf16x8*)&Ws[wo_l * 64 + ((wcg + 8) ^ sw)] = w1;
    }
    __syncthreads();
#pragma unroll
    for (int s = 0; s < 2; ++s) {
      int c8 = s * 32 + l4 * 8;
      bf16x8 afr[4], bfr[2];
#pragma unroll
      for (int m = 0; m < 4; ++m) {
        int r = moff + m * 16 + l15;
        afr[m] = *(const bf16x8*)&Xs[r * 64 + (c8 ^ ((r & 7) * 8))];
      }
#pragma unroll
      for (int n = 0; n < 2; ++n) {
        int r = ooff + n * 16 + l15;
        bfr[n] = *(const bf16x8*)&Ws[r * 64 + (c8 ^ ((r & 7) * 8))];
      }
#pragma unroll
      for (int m = 0; m < 4; ++m)
#pragma unroll
        for (int n = 0; n < 2; ++n)
          acc[m][n] = __builtin_amdgcn_mfma_f32_16x16x32_bf16(
              afr[m], bfr[n], acc[m][n], 0, 0, 0);
    }
    __syncthreads();
  }

  float b0 = bias[o0 + ooff + l15];
  float b1 = bias[o0 + ooff + 16 + l15];
#pragma unroll
  for (int m = 0; m < 4; ++m) {
    int mr = m0 + moff + m * 16 + l4 * 4;
#pragma unroll
    for (int reg = 0; reg < 4; ++reg) {
      if (mr + reg < M) {
        float v0 = (acc[m][0][reg] + b0) * scale;
        float v1 = (acc[m][1][reg] + b1) * scale;
        if (out_h) {
          out_h[(size_t)(mr + reg) * cC + o0 + ooff + l15] = (f16_t)v0;
          out_h[(size_t)(mr + reg) * cC + o0 + ooff + 16 + l15] = (f16_t)v1;
        } else {
          out[(size_t)(mr + reg) * cC + o0 + ooff + l15] = v0;
          out[(size_t)(mr + reg) * cC + o0 + ooff + 16 + l15] = v1;
        }
      }
    }
  }
}

// ---------------------------------------------------------------------------
// bf16-MFMA K/V projection: 512 threads, 128hw x 128o tile.
// SINGLE-buffered LDS (32 KB) with 2 barriers per K-iter; register prefetch
// of next tile stays in flight across the MFMA phase. Writes ONE fp16
// layout: outT[((b*8+h)*4096 + y*64+x)*32 + d]
__global__ __launch_bounds__(512) void proj_kv_mfma_k(
    const float* __restrict__ key, const float* __restrict__ value,
    const float* __restrict__ Wk, const float* __restrict__ bk,
    const float* __restrict__ Wv, const float* __restrict__ bv,
    f16_t* __restrict__ pkT, f16_t* __restrict__ pvT) {
  int z = blockIdx.z;
  int b = z >> 1;
  bool isv = z & 1;
  const float* X = (isv ? value : key) + (size_t)b * cC * cHW;
  const float* Wm = isv ? Wv : Wk;
  const float* bb = isv ? bv : bk;
  f16_t* outT = (isv ? pvT : pkT) + (size_t)b * cHEADS * cHW * cHD;
  int hw0 = blockIdx.x * 128;
  int o0 = blockIdx.y * 128;

  __shared__ bf16_t Xs[128 * 64];      // [hw][c] XOR-swizzled, 16KB
  __shared__ bf16_t Wf[16 * 64 * 8];   // frag order, 16KB

  int tid = threadIdx.x;
  int lane = tid & 63, w = tid >> 6;
  int l15 = lane & 15, l4 = lane >> 4;
  int cq = tid & 15;
  int hwg = tid >> 4;
  int wo_l = tid >> 2;
  int wcg = (tid & 3) * 16;
  int wks = wcg >> 5;
  int wl4 = (wcg & 31) >> 3;
  int wnt = wo_l >> 4, wl15 = wo_l & 15;
  int hwoff = (w >> 2) * 64;
  int nb = (w & 3) * 2;

  const float* xbase = X + hw0 + hwg * 4;
  const float* wbase = Wm + (size_t)(o0 + wo_l) * cC + wcg;

  f32x4 acc[4][2];
#pragma unroll
  for (int m = 0; m < 4; ++m)
#pragma unroll
    for (int n = 0; n < 2; ++n) acc[m][n] = (f32x4){0.f, 0.f, 0.f, 0.f};

  float4 xr4[4];
  float4 wr[4];
  auto issue = [&](int c0) {
#pragma unroll
    for (int i = 0; i < 4; ++i)
      xr4[i] = *(const float4*)(xbase + (size_t)(c0 + cq * 4 + i) * cHW);
    const float4* p = (const float4*)(wbase + c0);
    wr[0] = p[0]; wr[1] = p[1]; wr[2] = p[2]; wr[3] = p[3];
  };

  issue(0);
#pragma unroll
  for (int s = 0; s < 4; ++s) {
#pragma unroll
    for (int j = 0; j < 4; ++j) {
      int row = hwg * 4 + j;
      bf16x4 v = {(bf16_t)xr4[0][j], (bf16_t)xr4[1][j],
                  (bf16_t)xr4[2][j], (bf16_t)xr4[3][j]};
      *(bf16x4*)&Xs[row * 64 + ((cq * 4) ^ ((row & 7) * 8))] = v;
    }
    {
      bf16x8 v0 = {(bf16_t)wr[0].x, (bf16_t)wr[0].y, (bf16_t)wr[0].z, (bf16_t)wr[0].w,
                   (bf16_t)wr[1].x, (bf16_t)wr[1].y, (bf16_t)wr[1].z, (bf16_t)wr[1].w};
      bf16x8 v1 = {(bf16_t)wr[2].x, (bf16_t)wr[2].y, (bf16_t)wr[2].z, (bf16_t)wr[2].w,
                   (bf16_t)wr[3].x, (bf16_t)wr[3].y, (bf16_t)wr[3].z, (bf16_t)wr[3].w};
      *(bf16x8*)&Wf[(size_t)((wks * 8 + wnt) * 64 + wl4 * 16 + wl15) * 8] = v0;
      *(bf16x8*)&Wf[(size_t)((wks * 8 + wnt) * 64 + (wl4 + 1) * 16 + wl15) * 8] = v1;
    }
    if (s < 3) issue((s + 1) * 64);
    __syncthreads();
#pragma unroll
    for (int ks = 0; ks < 2; ++ks) {
      int c8 = ks * 32 + l4 * 8;
      bf16x8 bf0 = *(const bf16x8*)&Wf[(size_t)((ks * 8 + nb) * 64 + lane) * 8];
      bf16x8 bf1 = *(const bf16x8*)&Wf[(size_t)((ks * 8 + nb + 1) * 64 + lane) * 8];
#pragma unroll
      for (int m = 0; m < 4; ++m) {
        int r = hwoff + m * 16 + l15;
        bf16x8 a = *(const bf16x8*)&Xs[r * 64 + (c8 ^ ((r & 7) * 8))];
        acc[m][0] = __builtin_amdgcn_mfma_f32_16x16x32_bf16(a, bf0, acc[m][0], 0, 0, 0);
        acc[m][1] = __builtin_amdgcn_mfma_f32_16x16x32_bf16(a, bf1, acc[m][1], 0, 0, 0);
      }
    }
    if (s < 3) __syncthreads();
  }

  int osub = o0 + nb * 16;
  int head = osub >> 5;
  f16_t* obase = outT + (size_t)head * cHW * cHD;
  float bias0 = bb[osub + l15];
  float bias1 = bb[osub + 16 + l15];
#pragma unroll
  for (int m = 0; m < 4; ++m) {
    int hwr = hwoff + m * 16 + l4 * 4;
#pragma unroll
    for (int reg = 0; reg < 4; ++reg) {
      int hw = hw0 + hwr + reg;
      size_t rowoff = (size_t)hw * cHD;
      obase[rowoff + l15] = (f16_t)(acc[m][0][reg] + bias0);
      obase[rowoff + 16 + l15] = (f16_t)(acc[m][1][reg] + bias1);
    }
  }
}

// ---------------------------------------------------------------------------
// Attention: 1024-thread blocks = 16 waves = 4 queries x 4 heads, no LDS,
// no barriers — waves fully independent. 2 blocks/CU = 32 waves/CU (HW max).
// lane = (g16 = lane>>2 position group, ch = lane&3 channel quarter);
// QK via v_dot2_f32_f16, line-dense; er/ec lane-local for PV.
// 2-phase XCD scheme: g = xcd + 8*phase -> (b, 4-head pair).
__global__ __launch_bounds__(1024) void attn_k(
    const f16_t* __restrict__ pqh, const f16_t* __restrict__ pkT,
    const f16_t* __restrict__ pvT, const float* __restrict__ pts,
    float* __restrict__ out) {
  int bid = blockIdx.x;
  int xcd = bid & 7;
  int t = bid >> 3;                 // 0..149
  int phase = (t >= 75) ? 1 : 0;    // 2 phases
  int tq = t - phase * 75;          // 0..74
  int g = xcd + 8 * phase;          // 0..15
  int b = g >> 1;
  int pair = g & 1;
  int sub = threadIdx.x >> 8;       // 0..3 (query within block)
  int subtid = threadIdx.x & 255;
  int lane = subtid & 63;
  int wid = subtid >> 6;
  int n = pair * 4 + wid;           // head
  int q = tq * 4 + sub;             // 0..299

  float x = pts[((size_t)b * cNQ + q) * 2 + 0];
  float y = pts[((size_t)b * cNQ + q) * 2 + 1];
  float y0f = fminf(fmaxf(floorf(y), 0.f), (float)(cH - 1));
  float x0f = fminf(fmaxf(floorf(x), 0.f), (float)(cW - 1));
  float wy = y - y0f, wx = x - x0f;
  int y0 = (int)y0f, y1 = min(y0 + 1, cH - 1);
  int x0 = (int)x0f, x1 = min(x0 + 1, cW - 1);

  size_t hoff = (size_t)(b * cHEADS + n) * cHW * cHD;
  const f16_t* kTb = pkT + hoff;
  const f16_t* vTb = pvT + hoff;

  int g16 = lane >> 2, ch = lane & 3;

  // ---- q: this lane's 8-channel quarter (broadcast within g16 groups) ----
  f16x8 qv = *(const f16x8*)(pqh + ((size_t)b * cNQ + q) * cC + n * cHD + ch * 8);
  const f16x2* qp = (const f16x2*)&qv;

  // ---- QK: line-dense rounds; dot2 partial dots + 4-lane ch-reduce ----
  float wrowA[4], wcolA[4];
#pragma unroll
  for (int k = 0; k < 4; ++k) {
    int p = g16 * 4 + k;
    f16x8 a0 = *(const f16x8*)(kTb + (size_t)(y0 * cW + p) * cHD + ch * 8);
    f16x8 a1 = *(const f16x8*)(kTb + (size_t)(y1 * cW + p) * cHD + ch * 8);
    f16x8 b0 = *(const f16x8*)(kTb + (size_t)(p * cW + x0) * cHD + ch * 8);
    f16x8 b1 = *(const f16x8*)(kTb + (size_t)(p * cW + x1) * cHD + ch * 8);
    const f16x2* a0p = (const f16x2*)&a0;
    const f16x2* a1p = (const f16x2*)&a1;
    const f16x2* b0p = (const f16x2*)&b0;
    const f16x2* b1p = (const f16x2*)&b1;
    float s0 = 0.f, s1 = 0.f, t0 = 0.f, t1 = 0.f;
#pragma unroll
    for (int j2 = 0; j2 < 4; ++j2) {
      f16x2 qq = qp[j2];
      s0 = dot2acc(a0p[j2], qq, s0);
      s1 = dot2acc(a1p[j2], qq, s1);
      t0 = dot2acc(b0p[j2], qq, t0);
      t1 = dot2acc(b1p[j2], qq, t1);
    }
    float wrow = s0 + wy * (s1 - s0);
    float wcol = t0 + wx * (t1 - t0);
    wrow += __shfl_xor(wrow, 1, 64);
    wrow += __shfl_xor(wrow, 2, 64);
    wcol += __shfl_xor(wcol, 1, 64);
    wcol += __shfl_xor(wcol, 2, 64);
    wrowA[k] = wrow;
    wcolA[k] = wcol;
  }

  // ---- softmax over 128 (each position duplicated in 4 ch-lanes) ----
  float m = -1e30f;
#pragma unroll
  for (int k = 0; k < 4; ++k) m = fmaxf(m, fmaxf(wrowA[k], wcolA[k]));
#pragma unroll
  for (int sh = 4; sh <= 32; sh <<= 1) m = fmaxf(m, __shfl_xor(m, sh, 64));
  float er[4], ec[4];
  float ssl = 0.f;
#pragma unroll
  for (int k = 0; k < 4; ++k) {
    er[k] = __expf(wrowA[k] - m);
    ec[k] = __expf(wcolA[k] - m);
    ssl += er[k] + ec[k];
  }
  float ssum = ssl;
#pragma unroll
  for (int sh = 4; sh <= 32; sh <<= 1) ssum += __shfl_xor(ssum, sh, 64);

  // ---- PV: loads in-loop (compiler schedules); weights lane-local ----
  float omwy = 1.f - wy, omwx = 1.f - wx;
  float acc[8];
#pragma unroll
  for (int j = 0; j < 8; ++j) acc[j] = 0.f;
#pragma unroll
  for (int k = 0; k < 4; ++k) {
    int p = g16 * 4 + k;
    f16x8 r0 = *(const f16x8*)(vTb + (size_t)(y0 * cW + p) * cHD + ch * 8);
    f16x8 r1 = *(const f16x8*)(vTb + (size_t)(y1 * cW + p) * cHD + ch * 8);
    f16x8 c0 = *(const f16x8*)(vTb + (size_t)(p * cW + x0) * cHD + ch * 8);
    f16x8 c1 = *(const f16x8*)(vTb + (size_t)(p * cW + x1) * cHD + ch * 8);
    float wr0 = er[k] * omwy, wr1 = er[k] * wy;
    float wc0 = ec[k] * omwx, wc1 = ec[k] * wx;
#pragma unroll
    for (int j = 0; j < 8; ++j) {
      acc[j] += wr0 * (float)r0[j] + wr1 * (float)r1[j] +
                wc0 * (float)c0[j] + wc1 * (float)c1[j];
    }
  }
#pragma unroll
  for (int sh = 4; sh <= 32; sh <<= 1)
#pragma unroll
    for (int j = 0; j < 8; ++j) acc[j] += __shfl_xor(acc[j], sh, 64);

  float inv = 1.f / ssum;
  if (lane < 4) {
    float* op = out + ((size_t)b * cNQ + q) * cC + n * cHD + ch * 8;
    float4 o0 = {acc[0] * inv, acc[1] * inv, acc[2] * inv, acc[3] * inv};
    float4 o1 = {acc[4] * inv, acc[5] * inv, acc[6] * inv, acc[7] * inv};
    *(float4*)op = o0;
    *(float4*)(op + 4) = o1;
  }
}

extern "C" void kernel_launch(void* const* d_in, const int* in_sizes, int n_in,
                              void* d_out, int out_size, void* d_ws, size_t ws_size,
                              hipStream_t stream) {
  const float* query = (const float*)d_in[0];
  const float* key   = (const float*)d_in[1];
  const float* value = (const float*)d_in[2];
  const float* pts   = (const float*)d_in[3];
  const float* Wq = (const float*)d_in[4];
  const float* bq = (const float*)d_in[5];
  const float* Wk = (const float*)d_in[6];
  const float* bk = (const float*)d_in[7];
  const float* Wv = (const float*)d_in[8];
  const float* bv = (const float*)d_in[9];
  const float* Wo = (const float*)d_in[10];
  const float* bo = (const float*)d_in[11];
  float* out = (float*)d_out;

  const size_t kvsz = (size_t)cB * cC * cHW;
  f16_t* pqh = (f16_t*)d_ws;                          // 2400*256 f16
  f16_t* pkT = pqh + (size_t)cM * cC;
  f16_t* pvT = pkT + kvsz;
  float* ao = (float*)(pvT + kvsz);                   // 2400*256 f32

  proj_mfma_k<<<dim3((cM + 127) / 128, cC / 64), 256, 0, stream>>>(
      query, Wq, bq, nullptr, pqh, cSCALE, cM);
  proj_kv_mfma_k<<<dim3(cHW / 128, cC / 128, cB * 2), 512, 0, stream>>>(
      key, value, Wk, bk, Wv, bv, pkT, pvT);
  attn_k<<<cB * cNQ * 2 / 4, 1024, 0, stream>>>(pqh, pkT, pvT, pts, ao);
  proj_mfma_k<<<dim3((cM + 127) / 128, cC / 64), 256, 0, stream>>>(
      ao, Wo, bo, out, nullptr, 1.0f, cM);
}

// Round 21
// 95.512 us; speedup vs baseline: 1.0461x; 1.0461x over previous
//
#include <hip/hip_runtime.h>
#include <hip/hip_bf16.h>
#include <math.h>

constexpr int cB = 8, cNQ = 300, cC = 256, cH = 64, cW = 64, cHEADS = 8, cHD = 32;
constexpr int cHW = cH * cW;
constexpr int cM = cB * cNQ;  // 2400
constexpr float cSCALE = 0.1767766952966369f; // 32^-0.5

typedef __bf16 bf16_t;
typedef bf16_t bf16x4 __attribute__((ext_vector_type(4)));
typedef bf16_t bf16x8 __attribute__((ext_vector_type(8)));
typedef float f32x4 __attribute__((ext_vector_type(4)));
typedef _Float16 f16_t;
typedef f16_t f16x2 __attribute__((ext_vector_type(2)));
typedef f16_t f16x8 __attribute__((ext_vector_type(8)));

__device__ __forceinline__ float dot2acc(f16x2 a, f16x2 b, float c) {
#if __has_builtin(__builtin_amdgcn_fdot2)
  return __builtin_amdgcn_fdot2(a, b, c, false);
#else
  return c + (float)a.x * (float)b.x + (float)a.y * (float)b.y;
#endif
}

// ---------------------------------------------------------------------------
// MFMA GEMM: out[m,n] = (dot(X[m,:],Wt[n,:]) + bias[n])*scale. f16 out if out_h.
__global__ __launch_bounds__(256) void proj_mfma_k(
    const float* __restrict__ X, const float* __restrict__ Wt,
    const float* __restrict__ bias, float* __restrict__ out,
    f16_t* __restrict__ out_h, float scale, int M) {
  __shared__ bf16_t Xs[128 * 64];
  __shared__ bf16_t Ws[64 * 64];
  int m0 = blockIdx.x * 128;
  int o0 = blockIdx.y * 64;
  int tid = threadIdx.x;
  int lane = tid & 63, w = tid >> 6;
  int moff = (w & 1) * 64, ooff = (w >> 1) * 32;
  int l15 = lane & 15, l4 = lane >> 4;
  int srow = tid >> 1;
  int schalf = (tid & 1) * 32;
  int wo_l = tid >> 2;
  int wcg = (tid & 3) * 16;

  f32x4 acc[4][2];
#pragma unroll
  for (int m = 0; m < 4; ++m)
#pragma unroll
    for (int n = 0; n < 2; ++n) acc[m][n] = (f32x4){0.f, 0.f, 0.f, 0.f};

  for (int c0 = 0; c0 < cC; c0 += 64) {
    {
      int mrow = min(m0 + srow, M - 1);
      const float4* xr = (const float4*)(X + (size_t)mrow * cC + c0 + schalf);
      int sw = (srow & 7) * 8;
#pragma unroll
      for (int i = 0; i < 4; ++i) {
        float4 a = xr[i * 2], b4 = xr[i * 2 + 1];
        bf16x8 v = {(bf16_t)a.x, (bf16_t)a.y, (bf16_t)a.z, (bf16_t)a.w,
                    (bf16_t)b4.x, (bf16_t)b4.y, (bf16_t)b4.z, (bf16_t)b4.w};
        *(bf16x8*)&Xs[srow * 64 + ((schalf + i * 8) ^ sw)] = v;
      }
    }
    {
      const float4* wr = (const float4*)(Wt + (size_t)(o0 + wo_l) * cC + c0 + wcg);
      float4 a = wr[0], b4 = wr[1], c4 = wr[2], d4 = wr[3];
      bf16x8 w0 = {(bf16_t)a.x, (bf16_t)a.y, (bf16_t)a.z, (bf16_t)a.w,
                   (bf16_t)b4.x, (bf16_t)b4.y, (bf16_t)b4.z, (bf16_t)b4.w};
      bf16x8 w1 = {(bf16_t)c4.x, (bf16_t)c4.y, (bf16_t)c4.z, (bf16_t)c4.w,
                   (bf16_t)d4.x, (bf16_t)d4.y, (bf16_t)d4.z, (bf16_t)d4.w};
      int sw = (wo_l & 7) * 8;
      *(bf16x8*)&Ws[wo_l * 64 + (wcg ^ sw)] = w0;
      *(bf16x8*)&Ws[wo_l * 64 + ((wcg + 8) ^ sw)] = w1;
    }
    __syncthreads();
#pragma unroll
    for (int s = 0; s < 2; ++s) {
      int c8 = s * 32 + l4 * 8;
      bf16x8 afr[4], bfr[2];
#pragma unroll
      for (int m = 0; m < 4; ++m) {
        int r = moff + m * 16 + l15;
        afr[m] = *(const bf16x8*)&Xs[r * 64 + (c8 ^ ((r & 7) * 8))];
      }
#pragma unroll
      for (int n = 0; n < 2; ++n) {
        int r = ooff + n * 16 + l15;
        bfr[n] = *(const bf16x8*)&Ws[r * 64 + (c8 ^ ((r & 7) * 8))];
      }
#pragma unroll
      for (int m = 0; m < 4; ++m)
#pragma unroll
        for (int n = 0; n < 2; ++n)
          acc[m][n] = __builtin_amdgcn_mfma_f32_16x16x32_bf16(
              afr[m], bfr[n], acc[m][n], 0, 0, 0);
    }
    __syncthreads();
  }

  float b0 = bias[o0 + ooff + l15];
  float b1 = bias[o0 + ooff + 16 + l15];
#pragma unroll
  for (int m = 0; m < 4; ++m) {
    int mr = m0 + moff + m * 16 + l4 * 4;
#pragma unroll
    for (int reg = 0; reg < 4; ++reg) {
      if (mr + reg < M) {
        float v0 = (acc[m][0][reg] + b0) * scale;
        float v1 = (acc[m][1][reg] + b1) * scale;
        if (out_h) {
          out_h[(size_t)(mr + reg) * cC + o0 + ooff + l15] = (f16_t)v0;
          out_h[(size_t)(mr + reg) * cC + o0 + ooff + 16 + l15] = (f16_t)v1;
        } else {
          out[(size_t)(mr + reg) * cC + o0 + ooff + l15] = v0;
          out[(size_t)(mr + reg) * cC + o0 + ooff + 16 + l15] = v1;
        }
      }
    }
  }
}

// ---------------------------------------------------------------------------
// bf16-MFMA K/V projection: 512 threads, 128hw x 128o tile.
// SINGLE-buffered LDS (32 KB) with 2 barriers per K-iter; register prefetch
// of next tile stays in flight across the MFMA phase. Writes ONE fp16
// layout: outT[((b*8+h)*4096 + y*64+x)*32 + d]
__global__ __launch_bounds__(512) void proj_kv_mfma_k(
    const float* __restrict__ key, const float* __restrict__ value,
    const float* __restrict__ Wk, const float* __restrict__ bk,
    const float* __restrict__ Wv, const float* __restrict__ bv,
    f16_t* __restrict__ pkT, f16_t* __restrict__ pvT) {
  int z = blockIdx.z;
  int b = z >> 1;
  bool isv = z & 1;
  const float* X = (isv ? value : key) + (size_t)b * cC * cHW;
  const float* Wm = isv ? Wv : Wk;
  const float* bb = isv ? bv : bk;
  f16_t* outT = (isv ? pvT : pkT) + (size_t)b * cHEADS * cHW * cHD;
  int hw0 = blockIdx.x * 128;
  int o0 = blockIdx.y * 128;

  __shared__ bf16_t Xs[128 * 64];      // [hw][c] XOR-swizzled, 16KB
  __shared__ bf16_t Wf[16 * 64 * 8];   // frag order, 16KB

  int tid = threadIdx.x;
  int lane = tid & 63, w = tid >> 6;
  int l15 = lane & 15, l4 = lane >> 4;
  int cq = tid & 15;
  int hwg = tid >> 4;
  int wo_l = tid >> 2;
  int wcg = (tid & 3) * 16;
  int wks = wcg >> 5;
  int wl4 = (wcg & 31) >> 3;
  int wnt = wo_l >> 4, wl15 = wo_l & 15;
  int hwoff = (w >> 2) * 64;
  int nb = (w & 3) * 2;

  const float* xbase = X + hw0 + hwg * 4;
  const float* wbase = Wm + (size_t)(o0 + wo_l) * cC + wcg;

  f32x4 acc[4][2];
#pragma unroll
  for (int m = 0; m < 4; ++m)
#pragma unroll
    for (int n = 0; n < 2; ++n) acc[m][n] = (f32x4){0.f, 0.f, 0.f, 0.f};

  float4 xr4[4];
  float4 wr[4];
  auto issue = [&](int c0) {
#pragma unroll
    for (int i = 0; i < 4; ++i)
      xr4[i] = *(const float4*)(xbase + (size_t)(c0 + cq * 4 + i) * cHW);
    const float4* p = (const float4*)(wbase + c0);
    wr[0] = p[0]; wr[1] = p[1]; wr[2] = p[2]; wr[3] = p[3];
  };

  issue(0);
#pragma unroll
  for (int s = 0; s < 4; ++s) {
#pragma unroll
    for (int j = 0; j < 4; ++j) {
      int row = hwg * 4 + j;
      bf16x4 v = {(bf16_t)xr4[0][j], (bf16_t)xr4[1][j],
                  (bf16_t)xr4[2][j], (bf16_t)xr4[3][j]};
      *(bf16x4*)&Xs[row * 64 + ((cq * 4) ^ ((row & 7) * 8))] = v;
    }
    {
      bf16x8 v0 = {(bf16_t)wr[0].x, (bf16_t)wr[0].y, (bf16_t)wr[0].z, (bf16_t)wr[0].w,
                   (bf16_t)wr[1].x, (bf16_t)wr[1].y, (bf16_t)wr[1].z, (bf16_t)wr[1].w};
      bf16x8 v1 = {(bf16_t)wr[2].x, (bf16_t)wr[2].y, (bf16_t)wr[2].z, (bf16_t)wr[2].w,
                   (bf16_t)wr[3].x, (bf16_t)wr[3].y, (bf16_t)wr[3].z, (bf16_t)wr[3].w};
      *(bf16x8*)&Wf[(size_t)((wks * 8 + wnt) * 64 + wl4 * 16 + wl15) * 8] = v0;
      *(bf16x8*)&Wf[(size_t)((wks * 8 + wnt) * 64 + (wl4 + 1) * 16 + wl15) * 8] = v1;
    }
    if (s < 3) issue((s + 1) * 64);
    __syncthreads();
#pragma unroll
    for (int ks = 0; ks < 2; ++ks) {
      int c8 = ks * 32 + l4 * 8;
      bf16x8 bf0 = *(const bf16x8*)&Wf[(size_t)((ks * 8 + nb) * 64 + lane) * 8];
      bf16x8 bf1 = *(const bf16x8*)&Wf[(size_t)((ks * 8 + nb + 1) * 64 + lane) * 8];
#pragma unroll
      for (int m = 0; m < 4; ++m) {
        int r = hwoff + m * 16 + l15;
        bf16x8 a = *(const bf16x8*)&Xs[r * 64 + (c8 ^ ((r & 7) * 8))];
        acc[m][0] = __builtin_amdgcn_mfma_f32_16x16x32_bf16(a, bf0, acc[m][0], 0, 0, 0);
        acc[m][1] = __builtin_amdgcn_mfma_f32_16x16x32_bf16(a, bf1, acc[m][1], 0, 0, 0);
      }
    }
    if (s < 3) __syncthreads();
  }

  int osub = o0 + nb * 16;
  int head = osub >> 5;
  f16_t* obase = outT + (size_t)head * cHW * cHD;
  float bias0 = bb[osub + l15];
  float bias1 = bb[osub + 16 + l15];
#pragma unroll
  for (int m = 0; m < 4; ++m) {
    int hwr = hwoff + m * 16 + l4 * 4;
#pragma unroll
    for (int reg = 0; reg < 4; ++reg) {
      int hw = hw0 + hwr + reg;
      size_t rowoff = (size_t)hw * cHD;
      obase[rowoff + l15] = (f16_t)(acc[m][0][reg] + bias0);
      obase[rowoff + 16 + l15] = (f16_t)(acc[m][1][reg] + bias1);
    }
  }
}

// ---------------------------------------------------------------------------
// Attention: 256-thr blocks (4 waves = 4 heads); each wave processes TWO
// queries interleaved (2x memory-level parallelism per wave). No LDS.
// lane = (g16 = lane>>2 position group, ch = lane&3 channel quarter);
// QK via v_dot2_f32_f16, line-dense; er/ec lane-local for PV.
// 2-phase XCD scheme: g = xcd + 8*phase -> (b, 4-head pair).
__global__ __launch_bounds__(256) void attn_k(
    const f16_t* __restrict__ pqh, const f16_t* __restrict__ pkT,
    const f16_t* __restrict__ pvT, const float* __restrict__ pts,
    float* __restrict__ out) {
  int bid = blockIdx.x;
  int xcd = bid & 7;
  int t = bid >> 3;                 // 0..299
  int phase = (t >= 150) ? 1 : 0;   // 2 phases
  int tq = t - phase * 150;         // 0..149
  int g = xcd + 8 * phase;          // 0..15
  int b = g >> 1;
  int pair = g & 1;
  int lane = threadIdx.x & 63;
  int wid = threadIdx.x >> 6;
  int n = pair * 4 + wid;           // head

  size_t hoff = (size_t)(b * cHEADS + n) * cHW * cHD;
  const f16_t* kTb = pkT + hoff;
  const f16_t* vTb = pvT + hoff;
  int g16 = lane >> 2, ch = lane & 3;

  // per-query state
  int qi[2];
  float wy[2], wx[2];
  int y0[2], y1[2], x0[2], x1[2];
  f16x8 qv[2];
#pragma unroll
  for (int qq = 0; qq < 2; ++qq) {
    int q = tq * 2 + qq;
    qi[qq] = q;
    float x = pts[((size_t)b * cNQ + q) * 2 + 0];
    float y = pts[((size_t)b * cNQ + q) * 2 + 1];
    float y0f = fminf(fmaxf(floorf(y), 0.f), (float)(cH - 1));
    float x0f = fminf(fmaxf(floorf(x), 0.f), (float)(cW - 1));
    wy[qq] = y - y0f;
    wx[qq] = x - x0f;
    y0[qq] = (int)y0f;
    y1[qq] = min(y0[qq] + 1, cH - 1);
    x0[qq] = (int)x0f;
    x1[qq] = min(x0[qq] + 1, cW - 1);
    qv[qq] = *(const f16x8*)(pqh + ((size_t)b * cNQ + q) * cC + n * cHD + ch * 8);
  }

  // ---- QK: both queries interleaved per round (8 loads in flight) ----
  float wrowA[2][4], wcolA[2][4];
#pragma unroll
  for (int k = 0; k < 4; ++k) {
    int p = g16 * 4 + k;
    f16x8 a0[2], a1[2], b0[2], b1[2];
#pragma unroll
    for (int qq = 0; qq < 2; ++qq) {
      a0[qq] = *(const f16x8*)(kTb + (size_t)(y0[qq] * cW + p) * cHD + ch * 8);
      a1[qq] = *(const f16x8*)(kTb + (size_t)(y1[qq] * cW + p) * cHD + ch * 8);
      b0[qq] = *(const f16x8*)(kTb + (size_t)(p * cW + x0[qq]) * cHD + ch * 8);
      b1[qq] = *(const f16x8*)(kTb + (size_t)(p * cW + x1[qq]) * cHD + ch * 8);
    }
#pragma unroll
    for (int qq = 0; qq < 2; ++qq) {
      const f16x2* a0p = (const f16x2*)&a0[qq];
      const f16x2* a1p = (const f16x2*)&a1[qq];
      const f16x2* b0p = (const f16x2*)&b0[qq];
      const f16x2* b1p = (const f16x2*)&b1[qq];
      const f16x2* qp = (const f16x2*)&qv[qq];
      float s0 = 0.f, s1 = 0.f, t0 = 0.f, t1 = 0.f;
#pragma unroll
      for (int j2 = 0; j2 < 4; ++j2) {
        f16x2 qq2 = qp[j2];
        s0 = dot2acc(a0p[j2], qq2, s0);
        s1 = dot2acc(a1p[j2], qq2, s1);
        t0 = dot2acc(b0p[j2], qq2, t0);
        t1 = dot2acc(b1p[j2], qq2, t1);
      }
      float wrow = s0 + wy[qq] * (s1 - s0);
      float wcol = t0 + wx[qq] * (t1 - t0);
      wrow += __shfl_xor(wrow, 1, 64);
      wrow += __shfl_xor(wrow, 2, 64);
      wcol += __shfl_xor(wcol, 1, 64);
      wcol += __shfl_xor(wcol, 2, 64);
      wrowA[qq][k] = wrow;
      wcolA[qq][k] = wcol;
    }
  }

  // ---- softmax per query ----
  float er[2][4], ec[2][4], inv[2];
#pragma unroll
  for (int qq = 0; qq < 2; ++qq) {
    float m = -1e30f;
#pragma unroll
    for (int k = 0; k < 4; ++k) m = fmaxf(m, fmaxf(wrowA[qq][k], wcolA[qq][k]));
#pragma unroll
    for (int sh = 4; sh <= 32; sh <<= 1) m = fmaxf(m, __shfl_xor(m, sh, 64));
    float ssl = 0.f;
#pragma unroll
    for (int k = 0; k < 4; ++k) {
      er[qq][k] = __expf(wrowA[qq][k] - m);
      ec[qq][k] = __expf(wcolA[qq][k] - m);
      ssl += er[qq][k] + ec[qq][k];
    }
    float ssum = ssl;
#pragma unroll
    for (int sh = 4; sh <= 32; sh <<= 1) ssum += __shfl_xor(ssum, sh, 64);
    inv[qq] = 1.f / ssum;
  }

  // ---- PV: both queries interleaved per round ----
  float acc[2][8];
#pragma unroll
  for (int qq = 0; qq < 2; ++qq)
#pragma unroll
    for (int j = 0; j < 8; ++j) acc[qq][j] = 0.f;
#pragma unroll
  for (int k = 0; k < 4; ++k) {
    int p = g16 * 4 + k;
    f16x8 r0[2], r1[2], c0[2], c1[2];
#pragma unroll
    for (int qq = 0; qq < 2; ++qq) {
      r0[qq] = *(const f16x8*)(vTb + (size_t)(y0[qq] * cW + p) * cHD + ch * 8);
      r1[qq] = *(const f16x8*)(vTb + (size_t)(y1[qq] * cW + p) * cHD + ch * 8);
      c0[qq] = *(const f16x8*)(vTb + (size_t)(p * cW + x0[qq]) * cHD + ch * 8);
      c1[qq] = *(const f16x8*)(vTb + (size_t)(p * cW + x1[qq]) * cHD + ch * 8);
    }
#pragma unroll
    for (int qq = 0; qq < 2; ++qq) {
      float wr0 = er[qq][k] * (1.f - wy[qq]), wr1 = er[qq][k] * wy[qq];
      float wc0 = ec[qq][k] * (1.f - wx[qq]), wc1 = ec[qq][k] * wx[qq];
#pragma unroll
      for (int j = 0; j < 8; ++j) {
        acc[qq][j] += wr0 * (float)r0[qq][j] + wr1 * (float)r1[qq][j] +
                      wc0 * (float)c0[qq][j] + wc1 * (float)c1[qq][j];
      }
    }
  }
#pragma unroll
  for (int qq = 0; qq < 2; ++qq) {
#pragma unroll
    for (int sh = 4; sh <= 32; sh <<= 1)
#pragma unroll
      for (int j = 0; j < 8; ++j) acc[qq][j] += __shfl_xor(acc[qq][j], sh, 64);
  }

  if (lane < 4) {
#pragma unroll
    for (int qq = 0; qq < 2; ++qq) {
      float* op = out + ((size_t)b * cNQ + qi[qq]) * cC + n * cHD + ch * 8;
      float4 o0 = {acc[qq][0] * inv[qq], acc[qq][1] * inv[qq],
                   acc[qq][2] * inv[qq], acc[qq][3] * inv[qq]};
      float4 o1 = {acc[qq][4] * inv[qq], acc[qq][5] * inv[qq],
                   acc[qq][6] * inv[qq], acc[qq][7] * inv[qq]};
      *(float4*)op = o0;
      *(float4*)(op + 4) = o1;
    }
  }
}

extern "C" void kernel_launch(void* const* d_in, const int* in_sizes, int n_in,
                              void* d_out, int out_size, void* d_ws, size_t ws_size,
                              hipStream_t stream) {
  const float* query = (const float*)d_in[0];
  const float* key   = (const float*)d_in[1];
  const float* value = (const float*)d_in[2];
  const float* pts   = (const float*)d_in[3];
  const float* Wq = (const float*)d_in[4];
  const float* bq = (const float*)d_in[5];
  const float* Wk = (const float*)d_in[6];
  const float* bk = (const float*)d_in[7];
  const float* Wv = (const float*)d_in[8];
  const float* bv = (const float*)d_in[9];
  const float* Wo = (const float*)d_in[10];
  const float* bo = (const float*)d_in[11];
  float* out = (float*)d_out;

  const size_t kvsz = (size_t)cB * cC * cHW;
  f16_t* pqh = (f16_t*)d_ws;                          // 2400*256 f16
  f16_t* pkT = pqh + (size_t)cM * cC;
  f16_t* pvT = pkT + kvsz;
  float* ao = (float*)(pvT + kvsz);                   // 2400*256 f32

  proj_mfma_k<<<dim3((cM + 127) / 128, cC / 64), 256, 0, stream>>>(
      query, Wq, bq, nullptr, pqh, cSCALE, cM);
  proj_kv_mfma_k<<<dim3(cHW / 128, cC / 128, cB * 2), 512, 0, stream>>>(
      key, value, Wk, bk, Wv, bv, pkT, pvT);
  attn_k<<<cB * cNQ, 256, 0, stream>>>(pqh, pkT, pvT, pts, ao);
  proj_mfma_k<<<dim3((cM + 127) / 128, cC / 64), 256, 0, stream>>>(
      ao, Wo, bo, out, nullptr, 1.0f, cM);
}

// Round 23
// 87.944 us; speedup vs baseline: 1.1361x; 1.0860x over previous
//
#include <hip/hip_runtime.h>
#include <hip/hip_bf16.h>
#include <math.h>

constexpr int cB = 8, cNQ = 300, cC = 256, cH = 64, cW = 64, cHEADS = 8, cHD = 32;
constexpr int cHW = cH * cW;
constexpr int cM = cB * cNQ;  // 2400
constexpr float cSCALE = 0.1767766952966369f; // 32^-0.5

typedef __bf16 bf16_t;
typedef bf16_t bf16x4 __attribute__((ext_vector_type(4)));
typedef bf16_t bf16x8 __attribute__((ext_vector_type(8)));
typedef float f32x4 __attribute__((ext_vector_type(4)));
typedef _Float16 f16_t;
typedef f16_t f16x2 __attribute__((ext_vector_type(2)));
typedef f16_t f16x8 __attribute__((ext_vector_type(8)));

__device__ __forceinline__ float dot2acc(f16x2 a, f16x2 b, float c) {
#if __has_builtin(__builtin_amdgcn_fdot2)
  return __builtin_amdgcn_fdot2(a, b, c, false);
#else
  return c + (float)a.x * (float)b.x + (float)a.y * (float)b.y;
#endif
}

// ---------------------------------------------------------------------------
// MFMA GEMM (f32 out), used for the output projection only.
__global__ __launch_bounds__(256) void proj_mfma_k(
    const float* __restrict__ X, const float* __restrict__ Wt,
    const float* __restrict__ bias, float* __restrict__ out,
    float scale, int M) {
  __shared__ bf16_t Xs[128 * 64];
  __shared__ bf16_t Ws[64 * 64];
  int m0 = blockIdx.x * 128;
  int o0 = blockIdx.y * 64;
  int tid = threadIdx.x;
  int lane = tid & 63, w = tid >> 6;
  int moff = (w & 1) * 64, ooff = (w >> 1) * 32;
  int l15 = lane & 15, l4 = lane >> 4;
  int srow = tid >> 1;
  int schalf = (tid & 1) * 32;
  int wo_l = tid >> 2;
  int wcg = (tid & 3) * 16;

  f32x4 acc[4][2];
#pragma unroll
  for (int m = 0; m < 4; ++m)
#pragma unroll
    for (int n = 0; n < 2; ++n) acc[m][n] = (f32x4){0.f, 0.f, 0.f, 0.f};

  for (int c0 = 0; c0 < cC; c0 += 64) {
    {
      int mrow = min(m0 + srow, M - 1);
      const float4* xr = (const float4*)(X + (size_t)mrow * cC + c0 + schalf);
      int sw = (srow & 7) * 8;
#pragma unroll
      for (int i = 0; i < 4; ++i) {
        float4 a = xr[i * 2], b4 = xr[i * 2 + 1];
        bf16x8 v = {(bf16_t)a.x, (bf16_t)a.y, (bf16_t)a.z, (bf16_t)a.w,
                    (bf16_t)b4.x, (bf16_t)b4.y, (bf16_t)b4.z, (bf16_t)b4.w};
        *(bf16x8*)&Xs[srow * 64 + ((schalf + i * 8) ^ sw)] = v;
      }
    }
    {
      const float4* wr = (const float4*)(Wt + (size_t)(o0 + wo_l) * cC + c0 + wcg);
      float4 a = wr[0], b4 = wr[1], c4 = wr[2], d4 = wr[3];
      bf16x8 w0 = {(bf16_t)a.x, (bf16_t)a.y, (bf16_t)a.z, (bf16_t)a.w,
                   (bf16_t)b4.x, (bf16_t)b4.y, (bf16_t)b4.z, (bf16_t)b4.w};
      bf16x8 w1 = {(bf16_t)c4.x, (bf16_t)c4.y, (bf16_t)c4.z, (bf16_t)c4.w,
                   (bf16_t)d4.x, (bf16_t)d4.y, (bf16_t)d4.z, (bf16_t)d4.w};
      int sw = (wo_l & 7) * 8;
      *(bf16x8*)&Ws[wo_l * 64 + (wcg ^ sw)] = w0;
      *(bf16x8*)&Ws[wo_l * 64 + ((wcg + 8) ^ sw)] = w1;
    }
    __syncthreads();
#pragma unroll
    for (int s = 0; s < 2; ++s) {
      int c8 = s * 32 + l4 * 8;
      bf16x8 afr[4], bfr[2];
#pragma unroll
      for (int m = 0; m < 4; ++m) {
        int r = moff + m * 16 + l15;
        afr[m] = *(const bf16x8*)&Xs[r * 64 + (c8 ^ ((r & 7) * 8))];
      }
#pragma unroll
      for (int n = 0; n < 2; ++n) {
        int r = ooff + n * 16 + l15;
        bfr[n] = *(const bf16x8*)&Ws[r * 64 + (c8 ^ ((r & 7) * 8))];
      }
#pragma unroll
      for (int m = 0; m < 4; ++m)
#pragma unroll
        for (int n = 0; n < 2; ++n)
          acc[m][n] = __builtin_amdgcn_mfma_f32_16x16x32_bf16(
              afr[m], bfr[n], acc[m][n], 0, 0, 0);
    }
    __syncthreads();
  }

  float b0 = bias[o0 + ooff + l15];
  float b1 = bias[o0 + ooff + 16 + l15];
#pragma unroll
  for (int m = 0; m < 4; ++m) {
    int mr = m0 + moff + m * 16 + l4 * 4;
#pragma unroll
    for (int reg = 0; reg < 4; ++reg) {
      if (mr + reg < M) {
        out[(size_t)(mr + reg) * cC + o0 + ooff + l15] =
            (acc[m][0][reg] + b0) * scale;
        out[(size_t)(mr + reg) * cC + o0 + ooff + 16 + l15] =
            (acc[m][1][reg] + b1) * scale;
      }
    }
  }
}

// ---------------------------------------------------------------------------
// Unified projection kernel, 512 threads, 128x128 tiles, 32 KB LDS.
// z < 16 : K/V projection (z = b*2+isv), X^T staging via 4x4 reg transpose,
//          writes fp16 outT[((b*8+h)*4096 + hw)*32 + d].
// z == 16: Q projection (row-major X staging), writes fp16 pqh[m][c]*SCALE.
__global__ __launch_bounds__(512) void unified_proj_k(
    const float* __restrict__ key, const float* __restrict__ value,
    const float* __restrict__ query,
    const float* __restrict__ Wk, const float* __restrict__ bk,
    const float* __restrict__ Wv, const float* __restrict__ bv,
    const float* __restrict__ Wq, const float* __restrict__ bq,
    f16_t* __restrict__ pkT, f16_t* __restrict__ pvT,
    f16_t* __restrict__ pqh) {
  __shared__ bf16_t Xs[128 * 64];      // 16KB
  __shared__ bf16_t Wf[16 * 64 * 8];   // 16KB, fragment order

  int z = blockIdx.z;
  int tid = threadIdx.x;
  int lane = tid & 63, w = tid >> 6;
  int l15 = lane & 15, l4 = lane >> 4;
  int wo_l = tid >> 2;                    // W o-row 0..127
  int wcg = (tid & 3) * 16;               // W c-offset {0,16,32,48}
  int wks = wcg >> 5;
  int wl4 = (wcg & 31) >> 3;
  int wnt = wo_l >> 4, wl15 = wo_l & 15;
  int hwoff = (w >> 2) * 64;              // wave row sub-tile
  int nb = (w & 3) * 2;                   // wave o sub-tile pair

  f32x4 acc[4][2];
#pragma unroll
  for (int m = 0; m < 4; ++m)
#pragma unroll
    for (int n = 0; n < 2; ++n) acc[m][n] = (f32x4){0.f, 0.f, 0.f, 0.f};

  if (z < 16) {
    // ================= K/V projection =================
    int b = z >> 1;
    bool isv = z & 1;
    const float* X = (isv ? value : key) + (size_t)b * cC * cHW;
    const float* Wm = isv ? Wv : Wk;
    const float* bb = isv ? bv : bk;
    f16_t* outT = (isv ? pvT : pkT) + (size_t)b * cHEADS * cHW * cHD;
    int hw0 = blockIdx.x * 128;
    int o0 = blockIdx.y * 128;

    int cq = tid & 15;                    // c = cq*4 + i
    int hwg = tid >> 4;                   // hw = hwg*4 + j
    const float* xbase = X + hw0 + hwg * 4;
    const float* wbase = Wm + (size_t)(o0 + wo_l) * cC + wcg;

    float4 xr4[4];
    float4 wr[4];
    auto issue = [&](int c0) {
#pragma unroll
      for (int i = 0; i < 4; ++i)
        xr4[i] = *(const float4*)(xbase + (size_t)(c0 + cq * 4 + i) * cHW);
      const float4* p = (const float4*)(wbase + c0);
      wr[0] = p[0]; wr[1] = p[1]; wr[2] = p[2]; wr[3] = p[3];
    };

    issue(0);
#pragma unroll
    for (int s = 0; s < 4; ++s) {
#pragma unroll
      for (int j = 0; j < 4; ++j) {
        int row = hwg * 4 + j;
        bf16x4 v = {(bf16_t)xr4[0][j], (bf16_t)xr4[1][j],
                    (bf16_t)xr4[2][j], (bf16_t)xr4[3][j]};
        *(bf16x4*)&Xs[row * 64 + ((cq * 4) ^ ((row & 7) * 8))] = v;
      }
      {
        bf16x8 v0 = {(bf16_t)wr[0].x, (bf16_t)wr[0].y, (bf16_t)wr[0].z, (bf16_t)wr[0].w,
                     (bf16_t)wr[1].x, (bf16_t)wr[1].y, (bf16_t)wr[1].z, (bf16_t)wr[1].w};
        bf16x8 v1 = {(bf16_t)wr[2].x, (bf16_t)wr[2].y, (bf16_t)wr[2].z, (bf16_t)wr[2].w,
                     (bf16_t)wr[3].x, (bf16_t)wr[3].y, (bf16_t)wr[3].z, (bf16_t)wr[3].w};
        *(bf16x8*)&Wf[(size_t)((wks * 8 + wnt) * 64 + wl4 * 16 + wl15) * 8] = v0;
        *(bf16x8*)&Wf[(size_t)((wks * 8 + wnt) * 64 + (wl4 + 1) * 16 + wl15) * 8] = v1;
      }
      if (s < 3) issue((s + 1) * 64);
      __syncthreads();
#pragma unroll
      for (int ks = 0; ks < 2; ++ks) {
        int c8 = ks * 32 + l4 * 8;
        bf16x8 bf0 = *(const bf16x8*)&Wf[(size_t)((ks * 8 + nb) * 64 + lane) * 8];
        bf16x8 bf1 = *(const bf16x8*)&Wf[(size_t)((ks * 8 + nb + 1) * 64 + lane) * 8];
#pragma unroll
        for (int m = 0; m < 4; ++m) {
          int r = hwoff + m * 16 + l15;
          bf16x8 a = *(const bf16x8*)&Xs[r * 64 + (c8 ^ ((r & 7) * 8))];
          acc[m][0] = __builtin_amdgcn_mfma_f32_16x16x32_bf16(a, bf0, acc[m][0], 0, 0, 0);
          acc[m][1] = __builtin_amdgcn_mfma_f32_16x16x32_bf16(a, bf1, acc[m][1], 0, 0, 0);
        }
      }
      if (s < 3) __syncthreads();
    }

    int osub = o0 + nb * 16;
    int head = osub >> 5;
    f16_t* obase = outT + (size_t)head * cHW * cHD;
    float bias0 = bb[osub + l15];
    float bias1 = bb[osub + 16 + l15];
#pragma unroll
    for (int m = 0; m < 4; ++m) {
      int hwr = hwoff + m * 16 + l4 * 4;
#pragma unroll
      for (int reg = 0; reg < 4; ++reg) {
        int hw = hw0 + hwr + reg;
        size_t rowoff = (size_t)hw * cHD;
        obase[rowoff + l15] = (f16_t)(acc[m][0][reg] + bias0);
        obase[rowoff + 16 + l15] = (f16_t)(acc[m][1][reg] + bias1);
      }
    }
  } else {
    // ================= Q projection =================
    if (blockIdx.x >= (cM + 127) / 128) return;  // 19 m-tiles
    int m0 = blockIdx.x * 128;
    int o0 = blockIdx.y * 128;

    int srow = tid >> 2;                  // m-local 0..127
    int scg = (tid & 3) * 16;             // c offset {0,16,32,48}, 16 c each
    const float* wbase = Wq + (size_t)(o0 + wo_l) * cC + wcg;

    float4 xa[4], wr[4];
    auto issue = [&](int c0) {
      int mrow = min(m0 + srow, cM - 1);
      const float4* xr = (const float4*)(query + (size_t)mrow * cC + c0 + scg);
      xa[0] = xr[0]; xa[1] = xr[1]; xa[2] = xr[2]; xa[3] = xr[3];
      const float4* p = (const float4*)(wbase + c0);
      wr[0] = p[0]; wr[1] = p[1]; wr[2] = p[2]; wr[3] = p[3];
    };

    issue(0);
#pragma unroll
    for (int s = 0; s < 4; ++s) {
      {
        int sw = (srow & 7) * 8;
        bf16x8 v0 = {(bf16_t)xa[0].x, (bf16_t)xa[0].y, (bf16_t)xa[0].z, (bf16_t)xa[0].w,
                     (bf16_t)xa[1].x, (bf16_t)xa[1].y, (bf16_t)xa[1].z, (bf16_t)xa[1].w};
        bf16x8 v1 = {(bf16_t)xa[2].x, (bf16_t)xa[2].y, (bf16_t)xa[2].z, (bf16_t)xa[2].w,
                     (bf16_t)xa[3].x, (bf16_t)xa[3].y, (bf16_t)xa[3].z, (bf16_t)xa[3].w};
        *(bf16x8*)&Xs[srow * 64 + (scg ^ sw)] = v0;
        *(bf16x8*)&Xs[srow * 64 + ((scg + 8) ^ sw)] = v1;
      }
      {
        bf16x8 v0 = {(bf16_t)wr[0].x, (bf16_t)wr[0].y, (bf16_t)wr[0].z, (bf16_t)wr[0].w,
                     (bf16_t)wr[1].x, (bf16_t)wr[1].y, (bf16_t)wr[1].z, (bf16_t)wr[1].w};
        bf16x8 v1 = {(bf16_t)wr[2].x, (bf16_t)wr[2].y, (bf16_t)wr[2].z, (bf16_t)wr[2].w,
                     (bf16_t)wr[3].x, (bf16_t)wr[3].y, (bf16_t)wr[3].z, (bf16_t)wr[3].w};
        *(bf16x8*)&Wf[(size_t)((wks * 8 + wnt) * 64 + wl4 * 16 + wl15) * 8] = v0;
        *(bf16x8*)&Wf[(size_t)((wks * 8 + wnt) * 64 + (wl4 + 1) * 16 + wl15) * 8] = v1;
      }
      if (s < 3) issue((s + 1) * 64);
      __syncthreads();
#pragma unroll
      for (int ks = 0; ks < 2; ++ks) {
        int c8 = ks * 32 + l4 * 8;
        bf16x8 bf0 = *(const bf16x8*)&Wf[(size_t)((ks * 8 + nb) * 64 + lane) * 8];
        bf16x8 bf1 = *(const bf16x8*)&Wf[(size_t)((ks * 8 + nb + 1) * 64 + lane) * 8];
#pragma unroll
        for (int m = 0; m < 4; ++m) {
          int r = hwoff + m * 16 + l15;
          bf16x8 a = *(const bf16x8*)&Xs[r * 64 + (c8 ^ ((r & 7) * 8))];
          acc[m][0] = __builtin_amdgcn_mfma_f32_16x16x32_bf16(a, bf0, acc[m][0], 0, 0, 0);
          acc[m][1] = __builtin_amdgcn_mfma_f32_16x16x32_bf16(a, bf1, acc[m][1], 0, 0, 0);
        }
      }
      if (s < 3) __syncthreads();
    }

    int osub = o0 + nb * 16;
    float bias0 = bq[osub + l15];
    float bias1 = bq[osub + 16 + l15];
#pragma unroll
    for (int m = 0; m < 4; ++m) {
      int mr = m0 + hwoff + m * 16 + l4 * 4;
#pragma unroll
      for (int reg = 0; reg < 4; ++reg) {
        if (mr + reg < cM) {
          pqh[(size_t)(mr + reg) * cC + osub + l15] =
              (f16_t)((acc[m][0][reg] + bias0) * cSCALE);
          pqh[(size_t)(mr + reg) * cC + osub + 16 + l15] =
              (f16_t)((acc[m][1][reg] + bias1) * cSCALE);
        }
      }
    }
  }
}

// ---------------------------------------------------------------------------
// Attention (round-17/19 proven form): one wave per (b,q,head); 256-thr
// blocks = 4 waves = 4 heads, no LDS/barriers. Line-dense loads:
// lane = (g16 = lane>>2 position group, ch = lane&3 channel quarter);
// QK via v_dot2_f32_f16; er/ec lane-local for PV. 2-phase XCD scheme.
__global__ __launch_bounds__(256) void attn_k(
    const f16_t* __restrict__ pqh, const f16_t* __restrict__ pkT,
    const f16_t* __restrict__ pvT, const float* __restrict__ pts,
    float* __restrict__ out) {
  int bid = blockIdx.x;
  int xcd = bid & 7;
  int t = bid >> 3;                 // 0..599
  int phase = (t >= cNQ) ? 1 : 0;
  int q = t - phase * cNQ;
  int g = xcd + 8 * phase;          // 0..15
  int b = g >> 1;
  int pair = g & 1;
  int lane = threadIdx.x & 63;
  int wid = threadIdx.x >> 6;
  int n = pair * 4 + wid;

  float x = pts[((size_t)b * cNQ + q) * 2 + 0];
  float y = pts[((size_t)b * cNQ + q) * 2 + 1];
  float y0f = fminf(fmaxf(floorf(y), 0.f), (float)(cH - 1));
  float x0f = fminf(fmaxf(floorf(x), 0.f), (float)(cW - 1));
  float wy = y - y0f, wx = x - x0f;
  int y0 = (int)y0f, y1 = min(y0 + 1, cH - 1);
  int x0 = (int)x0f, x1 = min(x0 + 1, cW - 1);

  size_t hoff = (size_t)(b * cHEADS + n) * cHW * cHD;
  const f16_t* kTb = pkT + hoff;
  const f16_t* vTb = pvT + hoff;

  int g16 = lane >> 2, ch = lane & 3;

  f16x8 qv = *(const f16x8*)(pqh + ((size_t)b * cNQ + q) * cC + n * cHD + ch * 8);
  const f16x2* qp = (const f16x2*)&qv;

  float wrowA[4], wcolA[4];
#pragma unroll
  for (int k = 0; k < 4; ++k) {
    int p = g16 * 4 + k;
    f16x8 a0 = *(const f16x8*)(kTb + (size_t)(y0 * cW + p) * cHD + ch * 8);
    f16x8 a1 = *(const f16x8*)(kTb + (size_t)(y1 * cW + p) * cHD + ch * 8);
    f16x8 b0 = *(const f16x8*)(kTb + (size_t)(p * cW + x0) * cHD + ch * 8);
    f16x8 b1 = *(const f16x8*)(kTb + (size_t)(p * cW + x1) * cHD + ch * 8);
    const f16x2* a0p = (const f16x2*)&a0;
    const f16x2* a1p = (const f16x2*)&a1;
    const f16x2* b0p = (const f16x2*)&b0;
    const f16x2* b1p = (const f16x2*)&b1;
    float s0 = 0.f, s1 = 0.f, t0 = 0.f, t1 = 0.f;
#pragma unroll
    for (int j2 = 0; j2 < 4; ++j2) {
      f16x2 qq = qp[j2];
      s0 = dot2acc(a0p[j2], qq, s0);
      s1 = dot2acc(a1p[j2], qq, s1);
      t0 = dot2acc(b0p[j2], qq, t0);
      t1 = dot2acc(b1p[j2], qq, t1);
    }
    float wrow = s0 + wy * (s1 - s0);
    float wcol = t0 + wx * (t1 - t0);
    wrow += __shfl_xor(wrow, 1, 64);
    wrow += __shfl_xor(wrow, 2, 64);
    wcol += __shfl_xor(wcol, 1, 64);
    wcol += __shfl_xor(wcol, 2, 64);
    wrowA[k] = wrow;
    wcolA[k] = wcol;
  }

  float m = -1e30f;
#pragma unroll
  for (int k = 0; k < 4; ++k) m = fmaxf(m, fmaxf(wrowA[k], wcolA[k]));
#pragma unroll
  for (int sh = 4; sh <= 32; sh <<= 1) m = fmaxf(m, __shfl_xor(m, sh, 64));
  float er[4], ec[4];
  float ssl = 0.f;
#pragma unroll
  for (int k = 0; k < 4; ++k) {
    er[k] = __expf(wrowA[k] - m);
    ec[k] = __expf(wcolA[k] - m);
    ssl += er[k] + ec[k];
  }
  float ssum = ssl;
#pragma unroll
  for (int sh = 4; sh <= 32; sh <<= 1) ssum += __shfl_xor(ssum, sh, 64);

  float omwy = 1.f - wy, omwx = 1.f - wx;
  float acc[8];
#pragma unroll
  for (int j = 0; j < 8; ++j) acc[j] = 0.f;
#pragma unroll
  for (int k = 0; k < 4; ++k) {
    int p = g16 * 4 + k;
    f16x8 r0 = *(const f16x8*)(vTb + (size_t)(y0 * cW + p) * cHD + ch * 8);
    f16x8 r1 = *(const f16x8*)(vTb + (size_t)(y1 * cW + p) * cHD + ch * 8);
    f16x8 c0 = *(const f16x8*)(vTb + (size_t)(p * cW + x0) * cHD + ch * 8);
    f16x8 c1 = *(const f16x8*)(vTb + (size_t)(p * cW + x1) * cHD + ch * 8);
    float wr0 = er[k] * omwy, wr1 = er[k] * wy;
    float wc0 = ec[k] * omwx, wc1 = ec[k] * wx;
#pragma unroll
    for (int j = 0; j < 8; ++j) {
      acc[j] += wr0 * (float)r0[j] + wr1 * (float)r1[j] +
                wc0 * (float)c0[j] + wc1 * (float)c1[j];
    }
  }
#pragma unroll
  for (int sh = 4; sh <= 32; sh <<= 1)
#pragma unroll
    for (int j = 0; j < 8; ++j) acc[j] += __shfl_xor(acc[j], sh, 64);

  float inv = 1.f / ssum;
  if (lane < 4) {
    float* op = out + ((size_t)b * cNQ + q) * cC + n * cHD + ch * 8;
    float4 o0 = {acc[0] * inv, acc[1] * inv, acc[2] * inv, acc[3] * inv};
    float4 o1 = {acc[4] * inv, acc[5] * inv, acc[6] * inv, acc[7] * inv};
    *(float4*)op = o0;
    *(float4*)(op + 4) = o1;
  }
}

extern "C" void kernel_launch(void* const* d_in, const int* in_sizes, int n_in,
                              void* d_out, int out_size, void* d_ws, size_t ws_size,
                              hipStream_t stream) {
  const float* query = (const float*)d_in[0];
  const float* key   = (const float*)d_in[1];
  const float* value = (const float*)d_in[2];
  const float* pts   = (const float*)d_in[3];
  const float* Wq = (const float*)d_in[4];
  const float* bq = (const float*)d_in[5];
  const float* Wk = (const float*)d_in[6];
  const float* bk = (const float*)d_in[7];
  const float* Wv = (const float*)d_in[8];
  const float* bv = (const float*)d_in[9];
  const float* Wo = (const float*)d_in[10];
  const float* bo = (const float*)d_in[11];
  float* out = (float*)d_out;

  const size_t kvsz = (size_t)cB * cC * cHW;
  f16_t* pqh = (f16_t*)d_ws;                          // 2400*256 f16
  f16_t* pkT = pqh + (size_t)cM * cC;
  f16_t* pvT = pkT + kvsz;
  float* ao = (float*)(pvT + kvsz);                   // 2400*256 f32

  // L0: K/V projection (z<16) + Q projection (z==16), one launch
  unified_proj_k<<<dim3(32, 2, 17), 512, 0, stream>>>(
      key, value, query, Wk, bk, Wv, bv, Wq, bq, pkT, pvT, pqh);
  // L1: attention
  attn_k<<<cB * cNQ * 2, 256, 0, stream>>>(pqh, pkT, pvT, pts, ao);
  // L2: output projection
  proj_mfma_k<<<dim3((cM + 127) / 128, cC / 64), 256, 0, stream>>>(
      ao, Wo, bo, out, 1.0f, cM);
}